// Round 1
// baseline (595.695 us; speedup 1.0000x reference)
//
#include <hip/hip_runtime.h>

typedef unsigned short u16;
typedef unsigned int u32;
typedef short s8v __attribute__((ext_vector_type(8)));   // 8 x bf16 bits (4 VGPRs)
typedef float f4v __attribute__((ext_vector_type(4)));   // MFMA accumulator

// ---------- helpers ----------
__device__ __forceinline__ u16 f2bf(float f) {
    u32 u = __float_as_uint(f);
    u += 0x7FFFu + ((u >> 16) & 1u);   // round-to-nearest-even
    return (u16)(u >> 16);
}

__device__ __forceinline__ void async_load16(const u16* g, u16* l) {
    // global -> LDS DMA, 16B per lane; LDS dest = wave-uniform base + lane*16
    __builtin_amdgcn_global_load_lds(
        (const __attribute__((address_space(1))) u32*)g,
        (__attribute__((address_space(3))) u32*)l,
        16, 0, 0);
}

// ---------- kernel 1: style + demod + modulated bf16 weights ----------
// grid (256 co, 8 b), 256 threads (thread = ci)
// Wmod layout: [b][t(9)][co(256)][ci(256)] bf16
__global__ void modulate_kernel(const float* __restrict__ norm_feat,  // [8][64]
                                const float* __restrict__ mod_w,      // [256][64]
                                const float* __restrict__ mod_b,      // [256]
                                const float* __restrict__ weight,     // [256][256][9]
                                u16* __restrict__ Wmod) {
    const int co = blockIdx.x;
    const int b  = blockIdx.y;
    const int ci = threadIdx.x;

    __shared__ float nf[64];
    __shared__ float red[256];

    if (ci < 64) nf[ci] = norm_feat[b * 64 + ci];
    __syncthreads();

    // style[b][ci]
    float s = mod_b[ci];
    #pragma unroll 8
    for (int d = 0; d < 64; ++d) s += nf[d] * mod_w[ci * 64 + d];

    // per-ci weight row (9 taps) and its square-sum
    float w9[9];
    const float* wp = weight + ((size_t)co * 256 + ci) * 9;
    float sq = 0.f;
    #pragma unroll
    for (int t = 0; t < 9; ++t) { w9[t] = wp[t]; sq += w9[t] * w9[t]; }

    red[ci] = sq * s * s;
    __syncthreads();
    for (int off = 128; off > 0; off >>= 1) {
        if (ci < off) red[ci] += red[ci + off];
        __syncthreads();
    }
    const float scale = 1.0f / 48.0f;              // 1/sqrt(256*9)
    const float demod = rsqrtf(scale * scale * red[0] + 1e-8f);
    const float coef  = scale * s * demod;

    #pragma unroll
    for (int t = 0; t < 9; ++t) {
        Wmod[(((size_t)b * 9 + t) * 256 + co) * 256 + ci] = f2bf(w9[t] * coef);
    }
}

// ---------- kernel 2: NCHW fp32 -> NHWC bf16 ----------
// grid (128 y, 8 b), 256 threads
__global__ void transpose_kernel(const float* __restrict__ fea,  // [8][256][128][128]
                                 u16* __restrict__ feaT) {       // [8][128][128][256]
    __shared__ float lds_t[64][129];
    const int y = blockIdx.x;
    const int b = blockIdx.y;
    const int tid = threadIdx.x;

    for (int c0 = 0; c0 < 256; c0 += 64) {
        #pragma unroll
        for (int r = 0; r < 32; ++r) {
            int i = r * 256 + tid;          // 0..8191
            int c = i >> 7;                 // 0..63
            int x = i & 127;
            lds_t[c][x] = fea[(((size_t)b * 256 + c0 + c) * 128 + y) * 128 + x];
        }
        __syncthreads();
        #pragma unroll
        for (int j = 0; j < 16; ++j) {
            int p  = j * 256 + tid;         // 0..4095 (32 c-pairs x 128 x)
            int cp = p & 31;
            int x  = p >> 5;
            int cl = cp * 2;
            float f0 = lds_t[cl][x];
            float f1 = lds_t[cl + 1][x];
            u32 u = (u32)f2bf(f0) | ((u32)f2bf(f1) << 16);
            *(u32*)&feaT[(((size_t)b * 128 + y) * 128 + x) * 256 + c0 + cl] = u;
        }
        __syncthreads();
    }
}

// ---------- kernel 3: MFMA conv (shift-GEMM) ----------
// grid (128 y, 2 co-blocks, 8 b), 256 threads = 4 waves
// block computes out[b][cb*128 .. +128)[y][0..128)
__global__ __launch_bounds__(256) void conv_mfma(
        const u16* __restrict__ Wmod,   // [8][9][256][256] bf16
        const u16* __restrict__ feaT,   // [8][128][128][256] bf16
        float* __restrict__ out) {      // [8][256][128][128]
    // rows 0..2: fea rows y-1..y+1 (x index shifted +1, cols 0 and 129 are zero pad)
    // row 3: permanent zero row for out-of-bounds y
    __shared__ u16 lds_fea[4][130][32];

    const int y   = blockIdx.x;
    const int cb  = blockIdx.y;
    const int b   = blockIdx.z;
    const int tid = threadIdx.x;
    const int lane = tid & 63;
    const int wave = tid >> 6;
    const int mw = wave & 1;        // co half (64)
    const int nw = wave >> 1;       // pixel half (64)
    const int l4  = lane >> 4;      // quad 0..3
    const int l15 = lane & 15;

    // init zero row + pad columns (persist across whole kernel)
    for (int i = tid; i < 130 * 32; i += 256) ((u16*)lds_fea[3])[i] = 0;
    if (tid < 192) {
        int r   = tid / 64;                       // 0..2
        int col = ((tid >> 5) & 1) ? 129 : 0;
        lds_fea[r][col][tid & 31] = 0;
    }

    const int rsel[3] = { (y == 0) ? 3 : 0, 1, (y == 127) ? 3 : 2 };

    f4v acc[4][4];
    #pragma unroll
    for (int i = 0; i < 4; ++i)
        #pragma unroll
        for (int j = 0; j < 4; ++j) acc[i][j] = (f4v)0.0f;

    const int dma_x  = lane >> 2;         // 0..15
    const int dma_ci = (lane & 3) * 8;    // 0,8,16,24

    for (int ci0 = 0; ci0 < 256; ci0 += 32) {
        __syncthreads();   // previous iteration's reads done before overwrite
        // stage fea chunk: 3 rows x 128 x x 32 ci, bf16, via global->LDS DMA
        #pragma unroll
        for (int i = 0; i < 6; ++i) {
            int q  = wave + 4 * i;        // 0..23, wave-uniform
            int r  = q >> 3;              // 0..2
            int xb = q & 7;               // 0..7
            int gy = y - 1 + r;
            if ((unsigned)gy < 128u) {
                int x = xb * 16 + dma_x;
                const u16* g = feaT + ((((size_t)b * 128 + gy) * 128 + x) * 256 + ci0 + dma_ci);
                async_load16(g, &lds_fea[r][1 + xb * 16][0]);
            }
        }
        __syncthreads();

        #pragma unroll
        for (int t = 0; t < 9; ++t) {
            const int kh = t / 3, kw = t % 3;
            const int r = rsel[kh];
            s8v afr[4], bfr[4];
            #pragma unroll
            for (int i = 0; i < 4; ++i) {
                const u16* ap = Wmod +
                    ((((size_t)b * 9 + t) * 256 + cb * 128 + mw * 64 + i * 16 + l15) * 256
                     + ci0 + l4 * 8);
                afr[i] = *(const s8v*)ap;
            }
            #pragma unroll
            for (int j = 0; j < 4; ++j) {
                bfr[j] = *(const s8v*)&lds_fea[r][nw * 64 + j * 16 + l15 + kw][l4 * 8];
            }
            #pragma unroll
            for (int i = 0; i < 4; ++i)
                #pragma unroll
                for (int j = 0; j < 4; ++j)
                    acc[i][j] = __builtin_amdgcn_mfma_f32_16x16x32_bf16(
                        afr[i], bfr[j], acc[i][j], 0, 0, 0);
        }
    }

    // epilogue: C/D layout col=lane&15 (pixel), row=quad*4+reg (co)
    const int co_base = cb * 128 + mw * 64 + l4 * 4;
    const int x_base  = nw * 64 + l15;
    #pragma unroll
    for (int i = 0; i < 4; ++i) {
        #pragma unroll
        for (int reg = 0; reg < 4; ++reg) {
            int co = co_base + i * 16 + reg;
            float* op = out + (((size_t)(b * 256 + co) * 128 + y) * 128 + x_base);
            #pragma unroll
            for (int j = 0; j < 4; ++j) op[j * 16] = acc[i][j][reg];
        }
    }
}

// ---------- launch ----------
extern "C" void kernel_launch(void* const* d_in, const int* in_sizes, int n_in,
                              void* d_out, int out_size, void* d_ws, size_t ws_size,
                              hipStream_t stream) {
    const float* fea       = (const float*)d_in[0];
    const float* norm_feat = (const float*)d_in[1];
    const float* mod_w     = (const float*)d_in[2];
    const float* mod_b     = (const float*)d_in[3];
    const float* weight    = (const float*)d_in[4];
    float* out = (float*)d_out;

    // workspace layout: Wmod bf16 = 8*9*256*256*2 = 9 MiB, then feaT bf16 = 64 MiB
    u16* Wmod = (u16*)d_ws;
    u16* feaT = (u16*)((char*)d_ws + 9u * 1024u * 1024u);

    modulate_kernel<<<dim3(256, 8), 256, 0, stream>>>(norm_feat, mod_w, mod_b, weight, Wmod);
    transpose_kernel<<<dim3(128, 8), 256, 0, stream>>>(fea, feaT);
    conv_mfma<<<dim3(128, 2, 8), 256, 0, stream>>>(Wmod, feaT, out);
}